// Round 7
// baseline (195.327 us; speedup 1.0000x reference)
//
#include <hip/hip_runtime.h>

#define ALPHA 0.9f
#define INV_ALPHA (1.0f / 0.9f)
#define EPS 1e-6f
#define A63  1.31002050866e-3f   // 0.9^63
#define A64  1.17901845780e-3f   // 0.9^64
#define A127 1.54453364e-6f      // 0.9^127

constexpr int T_DIM  = 4096;
constexpr int B_DIM  = 16;
constexpr int D_DIM  = 1024;
constexpr int N_DIM  = 64;
constexpr int NPROJ  = 192;   // 3*n
constexpr int NCHUNK = 64;    // chunks of 64 outputs, 64-step warmup

typedef float  f32x4   __attribute__((ext_vector_type(4)));
typedef __bf16 bf16x8  __attribute__((ext_vector_type(8)));
typedef unsigned short ushort8 __attribute__((ext_vector_type(8)));
typedef _Float16 f16x8 __attribute__((ext_vector_type(8)));
typedef _Float16 f16x4 __attribute__((ext_vector_type(4)));

__device__ __forceinline__ unsigned short f2bf(float f) {
  unsigned u = __builtin_bit_cast(unsigned, f);
  u += 0x7fffu + ((u >> 16) & 1u);
  return (unsigned short)(u >> 16);
}
__device__ __forceinline__ float bf2f(unsigned short h) {
  unsigned u = ((unsigned)h) << 16;
  return __builtin_bit_cast(float, u);
}

// ---------------- W pre-conversion: fp32 -> bf16 hi/lo (unchanged, proven) ----------------
__global__ __launch_bounds__(256) void convert_w(
    const float* __restrict__ W, unsigned short* __restrict__ whi,
    unsigned short* __restrict__ wlo)
{
  int i = blockIdx.x * 256 + threadIdx.x;
  int c = i >> 10, k = i & 1023;
  float v = W[i];
  unsigned short h = f2bf(v);
  unsigned short l = f2bf(v - bf2f(h));
  int off = (k >> 5) * (NPROJ * 32) + c * 32 + (k & 31);
  whi[off] = h;
  wlo[off] = l;
}

// ---------------- MFMA projection GEMM (unchanged, proven) ----------------
constexpr int BM = 128, BK = 32, NS = D_DIM / BK;

__global__ __launch_bounds__(512, 2) void proj_gemm(
    const float* __restrict__ x, const unsigned short* __restrict__ whi,
    const unsigned short* __restrict__ wlo, float* __restrict__ proj)
{
  __shared__ unsigned short As_hi[2][BM * BK];
  __shared__ unsigned short As_lo[2][BM * BK];
  __shared__ unsigned short Bs[2][2][NPROJ * BK];

  const int tid  = threadIdx.x;
  const int w    = tid >> 6, lane = tid & 63;
  const int wr   = w >> 2, wc = w & 3;
  const int fr   = lane & 15, fg = lane >> 4;
  const int row0 = blockIdx.x * BM;

  const int arow = tid >> 2, akq = (tid & 3) * 8;
  const float* aSrc = x + (size_t)(row0 + arow) * D_DIM + akq;

  f32x4 acc[4][3];
#pragma unroll
  for (int i = 0; i < 4; ++i)
#pragma unroll
    for (int j = 0; j < 3; ++j) acc[i][j] = (f32x4){0.f, 0.f, 0.f, 0.f};

  float4 a0, a1;

  auto loadA = [&](int s) {
    const float* p = aSrc + s * BK;
    a0 = *(const float4*)p;
    a1 = *(const float4*)(p + 4);
  };
  auto writeA = [&](int buf) {
    float v[8] = {a0.x, a0.y, a0.z, a0.w, a1.x, a1.y, a1.z, a1.w};
    ushort8 h, l;
#pragma unroll
    for (int i = 0; i < 8; ++i) {
      __bf16 hb = (__bf16)v[i];
      float  hf = (float)hb;
      __bf16 lb = (__bf16)(v[i] - hf);
      h[i] = __builtin_bit_cast(unsigned short, hb);
      l[i] = __builtin_bit_cast(unsigned short, lb);
    }
    *(ushort8*)&As_hi[buf][arow * BK + akq] = h;
    *(ushort8*)&As_lo[buf][arow * BK + akq] = l;
  };
  auto stageB = [&](int buf, int s) {
#pragma unroll
    for (int j = 0; j < 3; ++j) {
      const int f = (j * 8 + w) * 1024;
      const unsigned short* src;
      unsigned short* dst;
      if (f < 12288) {
        src = whi + (size_t)s * (NPROJ * 32) + (f >> 1);
        dst = &Bs[buf][0][f >> 1];
      } else {
        src = wlo + (size_t)s * (NPROJ * 32) + ((f - 12288) >> 1);
        dst = &Bs[buf][1][(f - 12288) >> 1];
      }
      __builtin_amdgcn_global_load_lds(
          (const __attribute__((address_space(1))) unsigned int*)(src) + lane * 4,
          (__attribute__((address_space(3))) unsigned int*)dst, 16, 0, 0);
    }
  };
  auto compute = [&](int buf) {
    bf16x8 ah[4], al[4];
#pragma unroll
    for (int ar = 0; ar < 4; ++ar) {
      const int off = (wr * 64 + ar * 16 + fr) * BK + fg * 8;
      ah[ar] = __builtin_bit_cast(bf16x8, *(const ushort8*)&As_hi[buf][off]);
      al[ar] = __builtin_bit_cast(bf16x8, *(const ushort8*)&As_lo[buf][off]);
    }
#pragma unroll
    for (int bc = 0; bc < 3; ++bc) {
      const int boff = (wc * 48 + bc * 16 + fr) * BK + fg * 8;
      bf16x8 bh = __builtin_bit_cast(bf16x8, *(const ushort8*)&Bs[buf][0][boff]);
      bf16x8 bl = __builtin_bit_cast(bf16x8, *(const ushort8*)&Bs[buf][1][boff]);
#pragma unroll
      for (int ar = 0; ar < 4; ++ar) {
        acc[ar][bc] = __builtin_amdgcn_mfma_f32_16x16x32_bf16(ah[ar], bh, acc[ar][bc], 0, 0, 0);
        acc[ar][bc] = __builtin_amdgcn_mfma_f32_16x16x32_bf16(ah[ar], bl, acc[ar][bc], 0, 0, 0);
        acc[ar][bc] = __builtin_amdgcn_mfma_f32_16x16x32_bf16(al[ar], bh, acc[ar][bc], 0, 0, 0);
      }
    }
  };

  loadA(0);
  stageB(0, 0);
  writeA(0);
  __syncthreads();

  int buf = 0;
  for (int s = 0; s < NS; ++s) {
    if (s + 1 < NS) {
      loadA(s + 1);
      stageB(buf ^ 1, s + 1);
    }
    compute(buf);
    if (s + 1 < NS) writeA(buf ^ 1);
    __syncthreads();
    buf ^= 1;
  }

#pragma unroll
  for (int ar = 0; ar < 4; ++ar) {
    const int row = row0 + wr * 64 + ar * 16 + fg * 4;
#pragma unroll
    for (int bc = 0; bc < 3; ++bc) {
      const int col = wc * 48 + bc * 16 + fr;
#pragma unroll
      for (int r = 0; r < 4; ++r)
        proj[(size_t)(row + r) * NPROJ + col] = acc[ar][bc][r];
    }
  }
}

// ---------------- prep: normalize k, emit compact f16 [kn|v|q] ----------------
__global__ __launch_bounds__(256) void prep_kernel(
    const float* __restrict__ proj, _Float16* __restrict__ pf16)
{
  const int w = threadIdx.x >> 6, lane = threadIdx.x & 63;
  const int idx = blockIdx.x * 4 + w;
  const float* p = proj + (size_t)idx * NPROJ;
  const float k = p[lane];
  const float v = p[64 + lane];
  const float q = p[128 + lane];
  float ss = k * k;
#pragma unroll
  for (int m = 1; m < 64; m <<= 1) ss += __shfl_xor(ss, m, 64);
  const float rn = 1.0f / (sqrtf(ss) + EPS);
  _Float16* o = pf16 + (size_t)idx * NPROJ;
  o[lane]       = (_Float16)(k * rn);
  o[64 + lane]  = (_Float16)v;
  o[128 + lane] = (_Float16)q;
}

// ---------------- UT-transform chunked scan: one wave per (b,chunk) ----------------
// d_hat_t = a^{-t} v_t - S_in.kn_t - a^{-1} sum_{tau<t} G[tau][t] d_hat_tau
// Sq_t = a^t ( [Htri x DTo]_t,i + CF * [Aux x B1]_t,i ),  CF = c? a^64 : a
__global__ __launch_bounds__(64) void scan_ut(
    const _Float16* __restrict__ pf16, const float* __restrict__ S0,
    float* __restrict__ out, float* __restrict__ Sfin)
{
  __shared__ __align__(16) _Float16 SA[64][72];  // Kn_w | S0L(c0) -> DTw
  __shared__ __align__(16) _Float16 SB[64][72];  // Kn_o -> BaseO
  __shared__ __align__(16) _Float16 SQ[64][72];  // Q -> G'raw -> DTo (c>0)
  __shared__ __align__(16) _Float16 HT[64][72];  // Htri        (-> KnwT c63)
  __shared__ __align__(16) _Float16 HP[64][72];  // H'raw | DTo(c0) (-> KnoT c63)
  __shared__ __align__(16) float    G32[64][68]; // Gw -> Go (f32 solve tables)
  __shared__ __align__(16) _Float16 VL[64][64];  // v (per phase)

  const int lane = threadIdx.x;
  const int fr = lane & 15, fg = lane >> 4;
  const int b = blockIdx.x & (B_DIM - 1), c = blockIdx.x >> 4;
  const int t0o = c * 64, t0w = t0o - 64;
  const bool c0 = (c == 0);

  auto stagePad = [&](_Float16 (*dst)[72], int t0, int sel) {
#pragma unroll
    for (int it = 0; it < 8; ++it) {
      int g = it * 64 + lane, t = g >> 3, c8 = g & 7;
      uint4 v = *(const uint4*)(pf16 + ((size_t)(t0 + t) * B_DIM + b) * NPROJ + sel + c8 * 8);
      *(uint4*)&dst[t][c8 * 8] = v;
    }
  };
  auto stageV = [&](int t0) {
#pragma unroll
    for (int it = 0; it < 8; ++it) {
      int g = it * 64 + lane, t = g >> 3, c8 = g & 7;
      const _Float16* src = pf16 + ((size_t)(t0 + t) * B_DIM + b) * NPROJ + 64 + c8 * 8;
      __builtin_amdgcn_global_load_lds(
          (const __attribute__((address_space(1))) unsigned int*)src,
          (__attribute__((address_space(3))) unsigned int*)((char*)&VL[0][0] + it * 1024),
          16, 0, 0);
    }
  };

  // Gram: D[tau][t] = sum_d A[tau][d]*B[t][d]; writes TBL[t][tau] (f16, optional tri mask tau<=t)
  auto gram_f16 = [&](_Float16 (*dst)[72], const _Float16 (*A)[72], const _Float16 (*B)[72], bool tri) {
#pragma unroll
    for (int ti = 0; ti < 4; ++ti)
#pragma unroll
      for (int tj = 0; tj < 4; ++tj) {
        f32x4 a = (f32x4){0.f, 0.f, 0.f, 0.f};
#pragma unroll
        for (int s = 0; s < 2; ++s) {
          f16x8 af = *(const f16x8*)&A[ti * 16 + fr][s * 32 + fg * 8];
          f16x8 bf = *(const f16x8*)&B[tj * 16 + fr][s * 32 + fg * 8];
          a = __builtin_amdgcn_mfma_f32_16x16x32_f16(af, bf, a, 0, 0, 0);
        }
        const int tt = tj * 16 + fr, tb = ti * 16 + fg * 4;
        f16x4 hv;
#pragma unroll
        for (int r = 0; r < 4; ++r) {
          float v = a[r];
          if (tri && (tb + r > tt)) v = 0.f;
          hv[r] = (_Float16)v;
        }
        *(f16x4*)&dst[tt][tb] = hv;
      }
  };
  // f32 solve table: G32[t][tau] = (tau<t) ? INV_ALPHA * D[tau][t] : 0
  auto gram_f32 = [&](const _Float16 (*A)[72], const _Float16 (*B)[72]) {
#pragma unroll
    for (int ti = 0; ti < 4; ++ti)
#pragma unroll
      for (int tj = 0; tj < 4; ++tj) {
        f32x4 a = (f32x4){0.f, 0.f, 0.f, 0.f};
#pragma unroll
        for (int s = 0; s < 2; ++s) {
          f16x8 af = *(const f16x8*)&A[ti * 16 + fr][s * 32 + fg * 8];
          f16x8 bf = *(const f16x8*)&B[tj * 16 + fr][s * 32 + fg * 8];
          a = __builtin_amdgcn_mfma_f32_16x16x32_f16(af, bf, a, 0, 0, 0);
        }
        const int tt = tj * 16 + fr, tb = ti * 16 + fg * 4;
        f32x4 g;
#pragma unroll
        for (int r = 0; r < 4; ++r)
          g[r] = (tb + r < tt) ? a[r] * INV_ALPHA : 0.f;
        *(f32x4*)&G32[tt][tb] = g;
      }
  };
  // 16-tile MFMA: acc[ti*4+tj] = sum_k A[trow][k]*B[tcol][k]
  auto mm16 = [&](const _Float16 (*A)[72], const _Float16 (*B)[72], f32x4* acc) {
#pragma unroll
    for (int ti = 0; ti < 4; ++ti)
#pragma unroll
      for (int tj = 0; tj < 4; ++tj) {
        f32x4 a = (f32x4){0.f, 0.f, 0.f, 0.f};
#pragma unroll
        for (int s = 0; s < 2; ++s) {
          f16x8 af = *(const f16x8*)&A[ti * 16 + fr][s * 32 + fg * 8];
          f16x8 bf = *(const f16x8*)&B[tj * 16 + fr][s * 32 + fg * 8];
          a = __builtin_amdgcn_mfma_f32_16x16x32_f16(af, bf, a, 0, 0, 0);
        }
        acc[ti * 4 + tj] = a;
      }
  };

  // serial triangular solve: lane owns component i; G32 broadcast reads
  auto solve = [&](const _Float16 (*basep)[72], bool useBase, _Float16 (*dT)[72]) {
    float d[64];
#pragma unroll
    for (int i = 0; i < 64; ++i) d[i] = 0.f;
    float vinv = 1.f;
#pragma unroll
    for (int t = 0; t < 64; ++t) {
      float a0 = 0.f, a1 = 0.f, a2 = 0.f, a3 = 0.f;
#pragma unroll
      for (int tc = 0; tc < 16; ++tc) {
        if (tc * 4 < t) {          // compile-time after unroll; masked region is 0
          f32x4 g = *(const f32x4*)&G32[t][tc * 4];
          a0 = fmaf(g[0], d[tc * 4 + 0], a0);
          a1 = fmaf(g[1], d[tc * 4 + 1], a1);
          a2 = fmaf(g[2], d[tc * 4 + 2], a2);
          a3 = fmaf(g[3], d[tc * 4 + 3], a3);
        }
      }
      float vv = (float)VL[t][lane];
      float dt = fmaf(vv, vinv, -((a0 + a1) + (a2 + a3)));
      if (useBase) dt -= (float)basep[t][lane];
      d[t] = dt;
      vinv *= INV_ALPHA;
      float dc = fminf(fmaxf(dt, -60000.f), 60000.f);
      dT[lane][t] = (_Float16)dc;
    }
  };

  // ---- staging ----
  if (c0) {
    stagePad(SB, t0o, 0);     // Kn_o
    stagePad(SQ, t0o, 128);   // Q
    stageV(t0o);
#pragma unroll
    for (int it = 0; it < 64; ++it) {
      int e = it * 64 + lane, i = e >> 6, j = e & 63;
      SA[i][j] = (_Float16)S0[(size_t)b * 4096 + e];
    }
  } else {
    stagePad(SA, t0w, 0);     // Kn_w
    stagePad(SB, t0o, 0);     // Kn_o
    stagePad(SQ, t0o, 128);   // Q
    stageV(t0w);              // v_w
  }
  __syncthreads();

  // ---- Grams needing Q ----
  gram_f16(HT, SB, SQ, true);        // Htri[t][tau] = (kn_o_tau . q_t), tau<=t
  if (!c0) {
    gram_f16(HP, SA, SQ, false);     // H'raw[t][tau_w] = (kn_w . q_t)
    __syncthreads();                 // Q reads done
    gram_f16(SQ, SA, SB, false);     // G'raw[t][tau_w] = (kn_w . kn_o_t) -> overwrites Q
    gram_f32(SA, SA);                // Gw -> G32
    __syncthreads();
    solve(nullptr, false, SA);       // warmup deltas -> DTw (overwrites Kn_w)
    __syncthreads();
    stageV(t0o);                     // v_o (latency covered by Go gram)
    gram_f32(SB, SB);                // Go -> G32
    __syncthreads();
    // BaseO = A63 * (G'raw x DTw)  -> SB
    f32x4 bacc[16];
    mm16(SQ, SA, bacc);
    __syncthreads();
#pragma unroll
    for (int ti = 0; ti < 4; ++ti)
#pragma unroll
      for (int tj = 0; tj < 4; ++tj)
#pragma unroll
        for (int r = 0; r < 4; ++r)
          SB[ti * 16 + fg * 4 + r][tj * 16 + fr] = (_Float16)(bacc[ti * 4 + tj][r] * A63);
    __syncthreads();
    solve(SB, true, SQ);             // output deltas -> DTo (overwrites G')
  } else {
    gram_f32(SB, SB);                // Go -> G32
    __syncthreads();
    // BaseO = 1.0 * (Kn_o x S0L) -> SB (buffer acc, then overwrite)
    f32x4 bacc[16];
    mm16(SB, SA, bacc);
    __syncthreads();
#pragma unroll
    for (int ti = 0; ti < 4; ++ti)
#pragma unroll
      for (int tj = 0; tj < 4; ++tj)
#pragma unroll
        for (int r = 0; r < 4; ++r)
          SB[ti * 16 + fg * 4 + r][tj * 16 + fr] = (_Float16)bacc[ti * 4 + tj][r];
    __syncthreads();
    solve(SB, true, HP);             // output deltas -> DTo (HP unused for c0)
  }
  __syncthreads();

  // ---- outputs: Sq = a^t (ACC2 + CF*ACC1) ----
  f32x4 acc2[16], acc1[16];
  mm16(HT, c0 ? HP : SQ, acc2);      // Htri x DTo
  mm16(c0 ? SQ : HP, SA, acc1);      // c0: Q x S0L ; else: H'raw x DTw
  const float CF = c0 ? ALPHA : A64;
  const float pwti[4] = {1.f, 0.1853020189f, 0.0343368382f, 0.006362685443f};
  const float pfg = (fg == 0) ? 1.f : (fg == 1) ? 0.6561f : (fg == 2) ? 0.43046721f : 0.282429536481f;
  const float pr[4] = {1.f, 0.9f, 0.81f, 0.729f};
#pragma unroll
  for (int ti = 0; ti < 4; ++ti)
#pragma unroll
    for (int tj = 0; tj < 4; ++tj)
#pragma unroll
      for (int r = 0; r < 4; ++r) {
        const int tl = ti * 16 + fg * 4 + r;
        const float Sq = (acc2[ti * 4 + tj][r] + CF * acc1[ti * 4 + tj][r]) * (pwti[ti] * pfg * pr[r]);
        const float sig = 1.0f / (1.0f + __expf(-Sq));
        out[(size_t)(t0o + tl) * 1024 + b * 64 + (tj * 16 + fr)] = Sq * Sq * sig;
      }

  // ---- final state (c == 63): Sfin = A63*(DTo x KnoT) + A127*(DTw x KnwT) ----
  if (c == NCHUNK - 1) {
    __syncthreads();
    auto transp = [&](_Float16 (*dst)[72], int t0) {   // dst[j][tau] = kn[t0+tau][j]
      f16x8 rv[8];
#pragma unroll
      for (int q8 = 0; q8 < 8; ++q8)
        rv[q8] = *(const f16x8*)(pf16 + ((size_t)(t0 + lane) * B_DIM + b) * NPROJ + q8 * 8);
#pragma unroll
      for (int q8 = 0; q8 < 8; ++q8)
#pragma unroll
        for (int e = 0; e < 8; ++e)
          dst[q8 * 8 + e][lane] = rv[q8][e];
    };
    transp(HT, t0w);   // KnwT
    transp(HP, t0o);   // KnoT
    __syncthreads();
    f32x4 aw[16], ao[16];
    mm16(SA, HT, aw);  // DTw[i][tau] x KnwT[j][tau] -> D[i][j]
    mm16(SQ, HP, ao);  // DTo x KnoT
#pragma unroll
    for (int ti = 0; ti < 4; ++ti)
#pragma unroll
      for (int tj = 0; tj < 4; ++tj)
#pragma unroll
        for (int r = 0; r < 4; ++r) {
          const int i = ti * 16 + fg * 4 + r, j = tj * 16 + fr;
          Sfin[((size_t)b * 64 + i) * 64 + j] =
              A63 * ao[ti * 4 + tj][r] + A127 * aw[ti * 4 + tj][r];
        }
  }
}

extern "C" void kernel_launch(void* const* d_in, const int* in_sizes, int n_in,
                              void* d_out, int out_size, void* d_ws, size_t ws_size,
                              hipStream_t stream)
{
  const float* x  = (const float*)d_in[0];
  const float* S0 = (const float*)d_in[1];
  const float* Wk = (const float*)d_in[2];
  float* out  = (float*)d_out;
  float* Sfin = out + (size_t)T_DIM * B_DIM * N_DIM;

  // ws layout: proj (50.33 MB) | whi (384 KB) | wlo (384 KB) | pf16 (24 MB)
  char* wsb = (char*)d_ws;
  float*          proj = (float*)(wsb);
  unsigned short* whi  = (unsigned short*)(wsb + 50331648);
  unsigned short* wlo  = (unsigned short*)(wsb + 50724864);
  _Float16*       pf16 = (_Float16*)(wsb + 51118080);

  convert_w<<<(NPROJ * D_DIM) / 256, 256, 0, stream>>>(Wk, whi, wlo);
  proj_gemm<<<(T_DIM * B_DIM) / BM, 512, 0, stream>>>(x, whi, wlo, proj);
  prep_kernel<<<(T_DIM * B_DIM) / 4, 256, 0, stream>>>(proj, pf16);
  scan_ut<<<B_DIM * NCHUNK, 64, 0, stream>>>(pf16, S0, out, Sfin);
}

// Round 8
// 167.623 us; speedup vs baseline: 1.1653x; 1.1653x over previous
//
#include <hip/hip_runtime.h>

#define ALPHA 0.9f
#define EPS 1e-6f
#define LOG2A  (-0.15200309344504995f)   // log2(0.9)
#define A64F   (1.1790184577738583e-3f)  // 0.9^64

constexpr int T_DIM  = 4096;
constexpr int B_DIM  = 16;
constexpr int D_DIM  = 1024;
constexpr int N_DIM  = 64;
constexpr int NPROJ  = 192;
constexpr int NCHUNK = 64;

typedef float  f32x4   __attribute__((ext_vector_type(4)));
typedef __bf16 bf16x8  __attribute__((ext_vector_type(8)));
typedef unsigned short ushort8 __attribute__((ext_vector_type(8)));
typedef _Float16 f16x8 __attribute__((ext_vector_type(8)));

__device__ __forceinline__ unsigned short f2bf(float f) {
  unsigned u = __builtin_bit_cast(unsigned, f);
  u += 0x7fffu + ((u >> 16) & 1u);
  return (unsigned short)(u >> 16);
}
__device__ __forceinline__ float bf2f(unsigned short h) {
  unsigned u = ((unsigned)h) << 16;
  return __builtin_bit_cast(float, u);
}
__device__ __forceinline__ float powA(float e) {   // ALPHA^e
  return exp2f(e * LOG2A);
}

// ---------------- W pre-conversion (unchanged) ----------------
__global__ __launch_bounds__(256) void convert_w(
    const float* __restrict__ W, unsigned short* __restrict__ whi,
    unsigned short* __restrict__ wlo)
{
  int i = blockIdx.x * 256 + threadIdx.x;
  int c = i >> 10, k = i & 1023;
  float v = W[i];
  unsigned short h = f2bf(v);
  unsigned short l = f2bf(v - bf2f(h));
  int off = (k >> 5) * (NPROJ * 32) + c * 32 + (k & 31);
  whi[off] = h;
  wlo[off] = l;
}

// ---------------- MFMA projection GEMM -> writes f16 directly ----------------
constexpr int BM = 128, BK = 32, NS = D_DIM / BK;

__global__ __launch_bounds__(512, 2) void proj_gemm(
    const float* __restrict__ x, const unsigned short* __restrict__ whi,
    const unsigned short* __restrict__ wlo, _Float16* __restrict__ pf16)
{
  __shared__ unsigned short As_hi[2][BM * BK];
  __shared__ unsigned short As_lo[2][BM * BK];
  __shared__ unsigned short Bs[2][2][NPROJ * BK];

  const int tid  = threadIdx.x;
  const int w    = tid >> 6, lane = tid & 63;
  const int wr   = w >> 2, wc = w & 3;
  const int fr   = lane & 15, fg = lane >> 4;
  const int row0 = blockIdx.x * BM;

  const int arow = tid >> 2, akq = (tid & 3) * 8;
  const float* aSrc = x + (size_t)(row0 + arow) * D_DIM + akq;

  f32x4 acc[4][3];
#pragma unroll
  for (int i = 0; i < 4; ++i)
#pragma unroll
    for (int j = 0; j < 3; ++j) acc[i][j] = (f32x4){0.f, 0.f, 0.f, 0.f};

  float4 a0, a1;

  auto loadA = [&](int s) {
    const float* p = aSrc + s * BK;
    a0 = *(const float4*)p;
    a1 = *(const float4*)(p + 4);
  };
  auto writeA = [&](int buf) {
    float v[8] = {a0.x, a0.y, a0.z, a0.w, a1.x, a1.y, a1.z, a1.w};
    ushort8 h, l;
#pragma unroll
    for (int i = 0; i < 8; ++i) {
      __bf16 hb = (__bf16)v[i];
      float  hf = (float)hb;
      __bf16 lb = (__bf16)(v[i] - hf);
      h[i] = __builtin_bit_cast(unsigned short, hb);
      l[i] = __builtin_bit_cast(unsigned short, lb);
    }
    *(ushort8*)&As_hi[buf][arow * BK + akq] = h;
    *(ushort8*)&As_lo[buf][arow * BK + akq] = l;
  };
  auto stageB = [&](int buf, int s) {
#pragma unroll
    for (int j = 0; j < 3; ++j) {
      const int f = (j * 8 + w) * 1024;
      const unsigned short* src;
      unsigned short* dst;
      if (f < 12288) {
        src = whi + (size_t)s * (NPROJ * 32) + (f >> 1);
        dst = &Bs[buf][0][f >> 1];
      } else {
        src = wlo + (size_t)s * (NPROJ * 32) + ((f - 12288) >> 1);
        dst = &Bs[buf][1][(f - 12288) >> 1];
      }
      __builtin_amdgcn_global_load_lds(
          (const __attribute__((address_space(1))) unsigned int*)(src) + lane * 4,
          (__attribute__((address_space(3))) unsigned int*)dst, 16, 0, 0);
    }
  };
  auto compute = [&](int buf) {
    bf16x8 ah[4], al[4];
#pragma unroll
    for (int ar = 0; ar < 4; ++ar) {
      const int off = (wr * 64 + ar * 16 + fr) * BK + fg * 8;
      ah[ar] = __builtin_bit_cast(bf16x8, *(const ushort8*)&As_hi[buf][off]);
      al[ar] = __builtin_bit_cast(bf16x8, *(const ushort8*)&As_lo[buf][off]);
    }
#pragma unroll
    for (int bc = 0; bc < 3; ++bc) {
      const int boff = (wc * 48 + bc * 16 + fr) * BK + fg * 8;
      bf16x8 bh = __builtin_bit_cast(bf16x8, *(const ushort8*)&Bs[buf][0][boff]);
      bf16x8 bl = __builtin_bit_cast(bf16x8, *(const ushort8*)&Bs[buf][1][boff]);
#pragma unroll
      for (int ar = 0; ar < 4; ++ar) {
        acc[ar][bc] = __builtin_amdgcn_mfma_f32_16x16x32_bf16(ah[ar], bh, acc[ar][bc], 0, 0, 0);
        acc[ar][bc] = __builtin_amdgcn_mfma_f32_16x16x32_bf16(ah[ar], bl, acc[ar][bc], 0, 0, 0);
        acc[ar][bc] = __builtin_amdgcn_mfma_f32_16x16x32_bf16(al[ar], bh, acc[ar][bc], 0, 0, 0);
      }
    }
  };

  loadA(0);
  stageB(0, 0);
  writeA(0);
  __syncthreads();

  int buf = 0;
  for (int s = 0; s < NS; ++s) {
    if (s + 1 < NS) {
      loadA(s + 1);
      stageB(buf ^ 1, s + 1);
    }
    compute(buf);
    if (s + 1 < NS) writeA(buf ^ 1);
    __syncthreads();
    buf ^= 1;
  }

#pragma unroll
  for (int ar = 0; ar < 4; ++ar) {
    const int row = row0 + wr * 64 + ar * 16 + fg * 4;
#pragma unroll
    for (int bc = 0; bc < 3; ++bc) {
      const int col = wc * 48 + bc * 16 + fr;
#pragma unroll
      for (int r = 0; r < 4; ++r)
        pf16[(size_t)(row + r) * NPROJ + col] = (_Float16)acc[ar][bc][r];
    }
  }
}

// ---------------- prep: normalize k in place (f16) ----------------
__global__ __launch_bounds__(256) void prep_kernel(_Float16* __restrict__ pf16)
{
  const int w = threadIdx.x >> 6, lane = threadIdx.x & 63;
  const int idx = blockIdx.x * 4 + w;
  _Float16* p = pf16 + (size_t)idx * NPROJ;
  const float k = (float)p[lane];
  float ss = k * k;
#pragma unroll
  for (int m = 1; m < 64; m <<= 1) ss += __shfl_xor(ss, m, 64);
  const float rn = 1.0f / (sqrtf(ss) + EPS);
  p[lane] = (_Float16)(k * rn);
}

// ---------------- chunked scan via state-matrix (SW) formulation ----------------
// Per (b,c): warmup 64 steps (from 0) -> SW (c0: SW=S0), then 64 output steps.
// delta_t + sum_{tau<t} a^{t-1-tau}(kn_tau.kn_t) delta_tau = v_t - a^t (SW.kn_t)
// Sq_t = a^{t+1}(SW q_t) + sum_{tau<=t} a^{t-tau}(kn_tau.q_t) delta_tau
__global__ __launch_bounds__(64) void scan_sw(
    const _Float16* __restrict__ pf16, const float* __restrict__ S0,
    float* __restrict__ out, float* __restrict__ Sfin)
{
  __shared__ __align__(16) _Float16 sK[64][72];
  __shared__ __align__(16) _Float16 sQ[64][72];   // Q; also KwT/KoT transposes
  __shared__ __align__(16) _Float16 sV[64][72];   // v; o-phase: combined base
  __shared__ __align__(16) _Float16 sSW[64][72];  // state matrix
  __shared__ __align__(16) _Float16 sDT[64][80];  // delta^T [i][tau]
  __shared__ __align__(16) _Float16 sBB[16][72];  // bridge partial [t][i]
  __shared__ __align__(16) float    sBB2[16][20]; // in-block G (f32)
  __shared__ __align__(16) _Float16 sGt[16][40];  // transient G/H tile (cols>=16 zero)

  const int lane = threadIdx.x;
  const int fr = lane & 15, fg = lane >> 4;
  const int b = blockIdx.x & (B_DIM - 1), c = blockIdx.x >> 4;
  const int t0o = c * 64;
  const bool c0 = (c == 0);

  // zero sDT (NaN-safe masked MFMA reads) and sGt
#pragma unroll
  for (int j = 0; j < 40; ++j) ((unsigned*)&sDT[0][0])[j * 64 + lane] = 0u;
#pragma unroll
  for (int j = 0; j < 5; ++j) ((unsigned*)&sGt[0][0])[j * 64 + lane] = 0u;

  auto stage64 = [&](_Float16 (*dst)[72], int t0, int sel) {
#pragma unroll
    for (int it = 0; it < 8; ++it) {
      int g = it * 64 + lane, t = g >> 3, c8 = g & 7;
      uint4 v = *(const uint4*)(pf16 + ((size_t)(t0 + t) * B_DIM + b) * NPROJ + sel + c8 * 8);
      *(uint4*)&dst[t][c8 * 8] = v;
    }
  };

  // K=64 gram/mm: value at (Arow = ra+fg*4+r, Brow = rb+fr)
  auto dotT = [&](const _Float16* A, int sa, int ra, const _Float16* B, int sb, int rb) {
    f32x4 a = (f32x4){0.f, 0.f, 0.f, 0.f};
    f16x8 af = *(const f16x8*)(A + (ra + fr) * sa + fg * 8);
    f16x8 bf = *(const f16x8*)(B + (rb + fr) * sb + fg * 8);
    a = __builtin_amdgcn_mfma_f32_16x16x32_f16(af, bf, a, 0, 0, 0);
    af = *(const f16x8*)(A + (ra + fr) * sa + 32 + fg * 8);
    bf = *(const f16x8*)(B + (rb + fr) * sb + 32 + fg * 8);
    a = __builtin_amdgcn_mfma_f32_16x16x32_f16(af, bf, a, 0, 0, 0);
    return a;
  };

  auto transposeK = [&]() {   // sQ[j][tau=lane] = sK[lane][j]
    f16x8 rv[8];
#pragma unroll
    for (int q8 = 0; q8 < 8; ++q8) rv[q8] = *(const f16x8*)&sK[lane][q8 * 8];
#pragma unroll
    for (int q8 = 0; q8 < 8; ++q8)
#pragma unroll
      for (int e = 0; e < 8; ++e) sQ[q8 * 8 + e][lane] = rv[q8][e];
  };

  // solve: forward substitution with MFMA bridges; writes sDT (W: scaled a^{63-t})
  auto solve = [&](bool isW) {
    for (int k = 0; k < 4; ++k) {
      if (k > 0) {
        f32x4 bacc[4];
#pragma unroll
        for (int ib = 0; ib < 4; ++ib) bacc[ib] = (f32x4){0.f, 0.f, 0.f, 0.f};
        for (int j = 0; j < k; ++j) {
          f32x4 g = dotT(&sK[0][0], 72, k * 16, &sK[0][0], 72, j * 16);
#pragma unroll
          for (int r = 0; r < 4; ++r) {
            const int tl = fg * 4 + r;
            const float e = isW ? (float)(16 * k + tl - 64)
                                : (float)(16 * (k - j) + tl - fr - 1);
            sGt[tl][fr] = (_Float16)(g[r] * powA(e));
          }
#pragma unroll
          for (int ib = 0; ib < 4; ++ib) {
            f16x8 af = *(const f16x8*)&sGt[fr][fg * 8];
            f16x8 bf = *(const f16x8*)&sDT[ib * 16 + fr][j * 16 + fg * 8];
            bacc[ib] = __builtin_amdgcn_mfma_f32_16x16x32_f16(af, bf, bacc[ib], 0, 0, 0);
          }
        }
#pragma unroll
        for (int ib = 0; ib < 4; ++ib)
#pragma unroll
          for (int r = 0; r < 4; ++r)
            sBB[fg * 4 + r][ib * 16 + fr] = (_Float16)bacc[ib][r];
      }
      {  // diagonal tile -> f32 in-block table (upper incl. diag = 0)
        f32x4 g = dotT(&sK[0][0], 72, k * 16, &sK[0][0], 72, k * 16);
#pragma unroll
        for (int r = 0; r < 4; ++r) {
          const int tl = fg * 4 + r;
          sBB2[tl][fr] = (fr < tl) ? g[r] * powA((float)(tl - fr - 1)) : 0.f;
        }
      }
      // serial 16 steps
      float d[16];
#pragma unroll
      for (int t = 0; t < 16; ++t) d[t] = 0.f;
#pragma unroll
      for (int t = 0; t < 16; ++t) {
        float base = (float)sV[k * 16 + t][lane];
        if (k > 0) base -= (float)sBB[t][lane];
        const f32x4 g0 = *(const f32x4*)&sBB2[t][0];
        const f32x4 g1 = *(const f32x4*)&sBB2[t][4];
        const f32x4 g2 = *(const f32x4*)&sBB2[t][8];
        const f32x4 g3 = *(const f32x4*)&sBB2[t][12];
        float s0 = g0[0] * d[0];  s0 = fmaf(g0[1], d[1], s0);
        s0 = fmaf(g0[2], d[2], s0); s0 = fmaf(g0[3], d[3], s0);
        float s1 = g1[0] * d[4];  s1 = fmaf(g1[1], d[5], s1);
        s1 = fmaf(g1[2], d[6], s1); s1 = fmaf(g1[3], d[7], s1);
        float s2 = g2[0] * d[8];  s2 = fmaf(g2[1], d[9], s2);
        s2 = fmaf(g2[2], d[10], s2); s2 = fmaf(g2[3], d[11], s2);
        float s3 = g3[0] * d[12]; s3 = fmaf(g3[1], d[13], s3);
        s3 = fmaf(g3[2], d[14], s3); s3 = fmaf(g3[3], d[15], s3);
        d[t] = base - ((s0 + s1) + (s2 + s3));
      }
#pragma unroll
      for (int t8 = 0; t8 < 2; ++t8) {
        f16x8 pack;
#pragma unroll
        for (int e = 0; e < 8; ++e) {
          const int tl = t8 * 8 + e;
          const float sc = isW ? powA((float)(63 - (16 * k + tl))) : 1.f;
          pack[e] = (_Float16)(d[tl] * sc);
        }
        *(f16x8*)&sDT[lane][k * 16 + t8 * 8] = pack;
      }
    }
  };

  // ---------------- phase W -> SW ----------------
  if (!c0) {
    stage64(sK, t0o - 64, 0);    // kn warmup
    stage64(sV, t0o - 64, 64);   // v warmup
    solve(true);                 // sDT = a^{63-tau} * delta_w
    transposeK();                // sQ = Kw^T
#pragma unroll
    for (int ti = 0; ti < 4; ++ti)
#pragma unroll
      for (int tj = 0; tj < 4; ++tj) {
        f32x4 a = dotT(&sDT[0][0], 80, ti * 16, &sQ[0][0], 72, tj * 16);
#pragma unroll
        for (int r = 0; r < 4; ++r)
          sSW[ti * 16 + fg * 4 + r][tj * 16 + fr] = (_Float16)a[r];
      }
  } else {
    // SW = S0
#pragma unroll
    for (int it = 0; it < 8; ++it) {
      const int row = it * 8 + (lane >> 3), col = (lane & 7) * 8;
      const float* src = S0 + (size_t)b * 4096 + row * 64 + col;
      const float4 v1 = *(const float4*)src;
      const float4 v2 = *(const float4*)(src + 4);
      f16x8 pk;
      pk[0] = (_Float16)v1.x; pk[1] = (_Float16)v1.y;
      pk[2] = (_Float16)v1.z; pk[3] = (_Float16)v1.w;
      pk[4] = (_Float16)v2.x; pk[5] = (_Float16)v2.y;
      pk[6] = (_Float16)v2.z; pk[7] = (_Float16)v2.w;
      *(f16x8*)&sSW[row][col] = pk;
    }
  }

  // ---------------- phase O ----------------
  stage64(sK, t0o, 0);     // kn out
  stage64(sQ, t0o, 128);   // q
  stage64(sV, t0o, 64);    // v

  // combined base: sV[t][i] = v - a^t (SW.kn_t)[i]
#pragma unroll
  for (int ti = 0; ti < 4; ++ti)
#pragma unroll
    for (int tj = 0; tj < 4; ++tj) {
      f32x4 a = dotT(&sK[0][0], 72, ti * 16, &sSW[0][0], 72, tj * 16);
#pragma unroll
      for (int r = 0; r < 4; ++r) {
        const int t = ti * 16 + fg * 4 + r, i = tj * 16 + fr;
        const float vo = (float)sV[t][i];
        sV[t][i] = (_Float16)(vo - powA((float)t) * a[r]);
      }
    }

  // warm part of Sq (held in regs): a^{t+1} (SW.q_t)[i]
  f32x4 sq[16];
#pragma unroll
  for (int ti = 0; ti < 4; ++ti)
#pragma unroll
    for (int tj = 0; tj < 4; ++tj) {
      f32x4 a = dotT(&sQ[0][0], 72, ti * 16, &sSW[0][0], 72, tj * 16);
#pragma unroll
      for (int r = 0; r < 4; ++r)
        a[r] *= powA((float)(ti * 16 + fg * 4 + r + 1));
      sq[ti * 4 + tj] = a;
    }

  solve(false);   // sDT = delta_o (raw)

  // in-phase part: sq += Htile x DT
#pragma unroll
  for (int tb = 0; tb < 4; ++tb)
#pragma unroll
    for (int qb = 0; qb < 4; ++qb) {
      if (qb <= tb) {
        f32x4 h = dotT(&sQ[0][0], 72, tb * 16, &sK[0][0], 72, qb * 16);
#pragma unroll
        for (int r = 0; r < 4; ++r) {
          const int tl = fg * 4 + r;
          const int t = tb * 16 + tl, tau = qb * 16 + fr;
          const float val = (tau <= t) ? h[r] * powA((float)(t - tau)) : 0.f;
          sGt[tl][fr] = (_Float16)val;
        }
#pragma unroll
        for (int ib = 0; ib < 4; ++ib) {
          f16x8 af = *(const f16x8*)&sGt[fr][fg * 8];
          f16x8 bf = *(const f16x8*)&sDT[ib * 16 + fr][qb * 16 + fg * 8];
          sq[tb * 4 + ib] = __builtin_amdgcn_mfma_f32_16x16x32_f16(af, bf, sq[tb * 4 + ib], 0, 0, 0);
        }
      }
    }

  // outputs
#pragma unroll
  for (int ti = 0; ti < 4; ++ti)
#pragma unroll
    for (int tj = 0; tj < 4; ++tj)
#pragma unroll
      for (int r = 0; r < 4; ++r) {
        const int t = ti * 16 + fg * 4 + r, i = tj * 16 + fr;
        const float Sq = sq[ti * 4 + tj][r];
        const float sig = 1.0f / (1.0f + __expf(-Sq));
        out[(size_t)(t0o + t) * 1024 + b * 64 + i] = Sq * Sq * sig;
      }

  // final state
  if (c == NCHUNK - 1) {
    // scale DT in place: a^{63-tau}
#pragma unroll
    for (int t8 = 0; t8 < 8; ++t8) {
      f16x8 v = *(const f16x8*)&sDT[lane][t8 * 8];
#pragma unroll
      for (int e = 0; e < 8; ++e)
        v[e] = (_Float16)((float)v[e] * powA((float)(63 - (t8 * 8 + e))));
      *(f16x8*)&sDT[lane][t8 * 8] = v;
    }
    transposeK();   // sQ = Ko^T
#pragma unroll
    for (int ti = 0; ti < 4; ++ti)
#pragma unroll
      for (int tj = 0; tj < 4; ++tj) {
        f32x4 so = dotT(&sDT[0][0], 80, ti * 16, &sQ[0][0], 72, tj * 16);
#pragma unroll
        for (int r = 0; r < 4; ++r) {
          const int i = ti * 16 + fg * 4 + r, j = tj * 16 + fr;
          Sfin[((size_t)b * 64 + i) * 64 + j] = A64F * (float)sSW[i][j] + so[r];
        }
      }
  }
}

extern "C" void kernel_launch(void* const* d_in, const int* in_sizes, int n_in,
                              void* d_out, int out_size, void* d_ws, size_t ws_size,
                              hipStream_t stream)
{
  const float* x  = (const float*)d_in[0];
  const float* S0 = (const float*)d_in[1];
  const float* Wk = (const float*)d_in[2];
  float* out  = (float*)d_out;
  float* Sfin = out + (size_t)T_DIM * B_DIM * N_DIM;

  // ws layout: pf16 (25.17 MB) | whi (384 KB) | wlo (384 KB)
  char* wsb = (char*)d_ws;
  _Float16*       pf16 = (_Float16*)(wsb);
  unsigned short* whi  = (unsigned short*)(wsb + 25165824);
  unsigned short* wlo  = (unsigned short*)(wsb + 25559040);

  convert_w<<<(NPROJ * D_DIM) / 256, 256, 0, stream>>>(Wk, whi, wlo);
  proj_gemm<<<(T_DIM * B_DIM) / BM, 512, 0, stream>>>(x, whi, wlo, pf16);
  prep_kernel<<<(T_DIM * B_DIM) / 4, 256, 0, stream>>>(pf16);
  scan_sw<<<B_DIM * NCHUNK, 64, 0, stream>>>(pf16, S0, out, Sfin);
}

// Round 9
// 146.242 us; speedup vs baseline: 1.3356x; 1.1462x over previous
//
#include <hip/hip_runtime.h>

#define ALPHA 0.9f
#define EPS 1e-6f
#define LOG2A  (-0.15200309344504995f)   // log2(0.9)
#define A64F   (1.1790184577738583e-3f)  // 0.9^64

constexpr int T_DIM  = 4096;
constexpr int B_DIM  = 16;
constexpr int D_DIM  = 1024;
constexpr int N_DIM  = 64;
constexpr int NPROJ  = 192;
constexpr int NCHUNK = 64;

typedef float  f32x4   __attribute__((ext_vector_type(4)));
typedef unsigned short ushort8 __attribute__((ext_vector_type(8)));
typedef _Float16 f16x8 __attribute__((ext_vector_type(8)));

__device__ __forceinline__ float powA(float e) {   // ALPHA^e
  return exp2f(e * LOG2A);
}

// ---------------- W pre-conversion: fp32 -> f16, frag-step layout ----------------
__global__ __launch_bounds__(256) void convert_w(
    const float* __restrict__ W, _Float16* __restrict__ w16)
{
  int i = blockIdx.x * 256 + threadIdx.x;
  int c = i >> 10, k = i & 1023;
  w16[(k >> 5) * (NPROJ * 32) + c * 32 + (k & 31)] = (_Float16)W[i];
}

// ---------------- MFMA projection GEMM: pure f16, writes f16 ----------------
constexpr int BM = 128, BK = 32, NS = D_DIM / BK;

__global__ __launch_bounds__(512, 2) void proj_gemm(
    const float* __restrict__ x, const _Float16* __restrict__ w16,
    _Float16* __restrict__ pf16)
{
  __shared__ _Float16 As[2][BM * BK];       // 16 KB
  __shared__ _Float16 Bs[2][NPROJ * BK];    // 24 KB

  const int tid  = threadIdx.x;
  const int w    = tid >> 6, lane = tid & 63;
  const int wr   = w >> 2, wc = w & 3;      // wave grid 2x4
  const int fr   = lane & 15, fg = lane >> 4;
  const int row0 = blockIdx.x * BM;

  const int arow = tid >> 2, akq = (tid & 3) * 8;
  const float* aSrc = x + (size_t)(row0 + arow) * D_DIM + akq;

  f32x4 acc[4][3];
#pragma unroll
  for (int i = 0; i < 4; ++i)
#pragma unroll
    for (int j = 0; j < 3; ++j) acc[i][j] = (f32x4){0.f, 0.f, 0.f, 0.f};

  float4 a0, a1;

  auto loadA = [&](int s) {
    const float* p = aSrc + s * BK;
    a0 = *(const float4*)p;
    a1 = *(const float4*)(p + 4);
  };
  auto writeA = [&](int buf) {
    f16x8 h;
    h[0] = (_Float16)a0.x; h[1] = (_Float16)a0.y;
    h[2] = (_Float16)a0.z; h[3] = (_Float16)a0.w;
    h[4] = (_Float16)a1.x; h[5] = (_Float16)a1.y;
    h[6] = (_Float16)a1.z; h[7] = (_Float16)a1.w;
    *(f16x8*)&As[buf][arow * BK + akq] = h;
  };
  auto stageB = [&](int buf, int s) {
#pragma unroll
    for (int j = 0; j < 2; ++j) {
      const int sl = j * 8 + w;              // 1 KB slice index, 12 slices total
      if (sl < 12) {
        const _Float16* src = w16 + (size_t)s * (NPROJ * 32) + sl * 512;
        __builtin_amdgcn_global_load_lds(
            (const __attribute__((address_space(1))) unsigned int*)(src) + lane * 4,
            (__attribute__((address_space(3))) unsigned int*)&Bs[buf][sl * 512],
            16, 0, 0);
      }
    }
  };
  auto compute = [&](int buf) {
    f16x8 af[4];
#pragma unroll
    for (int ar = 0; ar < 4; ++ar)
      af[ar] = *(const f16x8*)&As[buf][(wr * 64 + ar * 16 + fr) * BK + fg * 8];
#pragma unroll
    for (int bc = 0; bc < 3; ++bc) {
      f16x8 bf = *(const f16x8*)&Bs[buf][(wc * 48 + bc * 16 + fr) * BK + fg * 8];
#pragma unroll
      for (int ar = 0; ar < 4; ++ar)
        acc[ar][bc] = __builtin_amdgcn_mfma_f32_16x16x32_f16(af[ar], bf, acc[ar][bc], 0, 0, 0);
    }
  };

  loadA(0);
  stageB(0, 0);
  writeA(0);
  __syncthreads();

  int buf = 0;
  for (int s = 0; s < NS; ++s) {
    if (s + 1 < NS) {
      loadA(s + 1);
      stageB(buf ^ 1, s + 1);
    }
    compute(buf);
    if (s + 1 < NS) writeA(buf ^ 1);
    __syncthreads();
    buf ^= 1;
  }

#pragma unroll
  for (int ar = 0; ar < 4; ++ar) {
    const int row = row0 + wr * 64 + ar * 16 + fg * 4;
#pragma unroll
    for (int bc = 0; bc < 3; ++bc) {
      const int col = wc * 48 + bc * 16 + fr;
#pragma unroll
      for (int r = 0; r < 4; ++r)
        pf16[(size_t)(row + r) * NPROJ + col] = (_Float16)acc[ar][bc][r];
    }
  }
}

// ---------------- prep: normalize k in place (f16) ----------------
__global__ __launch_bounds__(256) void prep_kernel(_Float16* __restrict__ pf16)
{
  const int w = threadIdx.x >> 6, lane = threadIdx.x & 63;
  const int idx = blockIdx.x * 4 + w;
  _Float16* p = pf16 + (size_t)idx * NPROJ;
  const float k = (float)p[lane];
  float ss = k * k;
#pragma unroll
  for (int m = 1; m < 64; m <<= 1) ss += __shfl_xor(ss, m, 64);
  const float rn = 1.0f / (sqrtf(ss) + EPS);
  p[lane] = (_Float16)(k * rn);
}

// ---------------- chunked scan via state-matrix (SW) formulation (R8, frozen) ----------------
__global__ __launch_bounds__(64) void scan_sw(
    const _Float16* __restrict__ pf16, const float* __restrict__ S0,
    float* __restrict__ out, float* __restrict__ Sfin)
{
  __shared__ __align__(16) _Float16 sK[64][72];
  __shared__ __align__(16) _Float16 sQ[64][72];   // Q; also KwT/KoT transposes
  __shared__ __align__(16) _Float16 sV[64][72];   // v; o-phase: combined base
  __shared__ __align__(16) _Float16 sSW[64][72];  // state matrix
  __shared__ __align__(16) _Float16 sDT[64][80];  // delta^T [i][tau]
  __shared__ __align__(16) _Float16 sBB[16][72];  // bridge partial [t][i]
  __shared__ __align__(16) float    sBB2[16][20]; // in-block G (f32)
  __shared__ __align__(16) _Float16 sGt[16][40];  // transient G/H tile (cols>=16 zero)

  const int lane = threadIdx.x;
  const int fr = lane & 15, fg = lane >> 4;
  const int b = blockIdx.x & (B_DIM - 1), c = blockIdx.x >> 4;
  const int t0o = c * 64;
  const bool c0 = (c == 0);

#pragma unroll
  for (int j = 0; j < 40; ++j) ((unsigned*)&sDT[0][0])[j * 64 + lane] = 0u;
#pragma unroll
  for (int j = 0; j < 5; ++j) ((unsigned*)&sGt[0][0])[j * 64 + lane] = 0u;

  auto stage64 = [&](_Float16 (*dst)[72], int t0, int sel) {
#pragma unroll
    for (int it = 0; it < 8; ++it) {
      int g = it * 64 + lane, t = g >> 3, c8 = g & 7;
      uint4 v = *(const uint4*)(pf16 + ((size_t)(t0 + t) * B_DIM + b) * NPROJ + sel + c8 * 8);
      *(uint4*)&dst[t][c8 * 8] = v;
    }
  };

  auto dotT = [&](const _Float16* A, int sa, int ra, const _Float16* B, int sb, int rb) {
    f32x4 a = (f32x4){0.f, 0.f, 0.f, 0.f};
    f16x8 af = *(const f16x8*)(A + (ra + fr) * sa + fg * 8);
    f16x8 bf = *(const f16x8*)(B + (rb + fr) * sb + fg * 8);
    a = __builtin_amdgcn_mfma_f32_16x16x32_f16(af, bf, a, 0, 0, 0);
    af = *(const f16x8*)(A + (ra + fr) * sa + 32 + fg * 8);
    bf = *(const f16x8*)(B + (rb + fr) * sb + 32 + fg * 8);
    a = __builtin_amdgcn_mfma_f32_16x16x32_f16(af, bf, a, 0, 0, 0);
    return a;
  };

  auto transposeK = [&]() {   // sQ[j][tau=lane] = sK[lane][j]
    f16x8 rv[8];
#pragma unroll
    for (int q8 = 0; q8 < 8; ++q8) rv[q8] = *(const f16x8*)&sK[lane][q8 * 8];
#pragma unroll
    for (int q8 = 0; q8 < 8; ++q8)
#pragma unroll
      for (int e = 0; e < 8; ++e) sQ[q8 * 8 + e][lane] = rv[q8][e];
  };

  auto solve = [&](bool isW) {
    for (int k = 0; k < 4; ++k) {
      if (k > 0) {
        f32x4 bacc[4];
#pragma unroll
        for (int ib = 0; ib < 4; ++ib) bacc[ib] = (f32x4){0.f, 0.f, 0.f, 0.f};
        for (int j = 0; j < k; ++j) {
          f32x4 g = dotT(&sK[0][0], 72, k * 16, &sK[0][0], 72, j * 16);
#pragma unroll
          for (int r = 0; r < 4; ++r) {
            const int tl = fg * 4 + r;
            const float e = isW ? (float)(16 * k + tl - 64)
                                : (float)(16 * (k - j) + tl - fr - 1);
            sGt[tl][fr] = (_Float16)(g[r] * powA(e));
          }
#pragma unroll
          for (int ib = 0; ib < 4; ++ib) {
            f16x8 af = *(const f16x8*)&sGt[fr][fg * 8];
            f16x8 bf = *(const f16x8*)&sDT[ib * 16 + fr][j * 16 + fg * 8];
            bacc[ib] = __builtin_amdgcn_mfma_f32_16x16x32_f16(af, bf, bacc[ib], 0, 0, 0);
          }
        }
#pragma unroll
        for (int ib = 0; ib < 4; ++ib)
#pragma unroll
          for (int r = 0; r < 4; ++r)
            sBB[fg * 4 + r][ib * 16 + fr] = (_Float16)bacc[ib][r];
      }
      {
        f32x4 g = dotT(&sK[0][0], 72, k * 16, &sK[0][0], 72, k * 16);
#pragma unroll
        for (int r = 0; r < 4; ++r) {
          const int tl = fg * 4 + r;
          sBB2[tl][fr] = (fr < tl) ? g[r] * powA((float)(tl - fr - 1)) : 0.f;
        }
      }
      float d[16];
#pragma unroll
      for (int t = 0; t < 16; ++t) d[t] = 0.f;
#pragma unroll
      for (int t = 0; t < 16; ++t) {
        float base = (float)sV[k * 16 + t][lane];
        if (k > 0) base -= (float)sBB[t][lane];
        const f32x4 g0 = *(const f32x4*)&sBB2[t][0];
        const f32x4 g1 = *(const f32x4*)&sBB2[t][4];
        const f32x4 g2 = *(const f32x4*)&sBB2[t][8];
        const f32x4 g3 = *(const f32x4*)&sBB2[t][12];
        float s0 = g0[0] * d[0];  s0 = fmaf(g0[1], d[1], s0);
        s0 = fmaf(g0[2], d[2], s0); s0 = fmaf(g0[3], d[3], s0);
        float s1 = g1[0] * d[4];  s1 = fmaf(g1[1], d[5], s1);
        s1 = fmaf(g1[2], d[6], s1); s1 = fmaf(g1[3], d[7], s1);
        float s2 = g2[0] * d[8];  s2 = fmaf(g2[1], d[9], s2);
        s2 = fmaf(g2[2], d[10], s2); s2 = fmaf(g2[3], d[11], s2);
        float s3 = g3[0] * d[12]; s3 = fmaf(g3[1], d[13], s3);
        s3 = fmaf(g3[2], d[14], s3); s3 = fmaf(g3[3], d[15], s3);
        d[t] = base - ((s0 + s1) + (s2 + s3));
      }
#pragma unroll
      for (int t8 = 0; t8 < 2; ++t8) {
        f16x8 pack;
#pragma unroll
        for (int e = 0; e < 8; ++e) {
          const int tl = t8 * 8 + e;
          const float sc = isW ? powA((float)(63 - (16 * k + tl))) : 1.f;
          pack[e] = (_Float16)(d[tl] * sc);
        }
        *(f16x8*)&sDT[lane][k * 16 + t8 * 8] = pack;
      }
    }
  };

  // ---------------- phase W -> SW ----------------
  if (!c0) {
    stage64(sK, t0o - 64, 0);
    stage64(sV, t0o - 64, 64);
    solve(true);
    transposeK();
#pragma unroll
    for (int ti = 0; ti < 4; ++ti)
#pragma unroll
      for (int tj = 0; tj < 4; ++tj) {
        f32x4 a = dotT(&sDT[0][0], 80, ti * 16, &sQ[0][0], 72, tj * 16);
#pragma unroll
        for (int r = 0; r < 4; ++r)
          sSW[ti * 16 + fg * 4 + r][tj * 16 + fr] = (_Float16)a[r];
      }
  } else {
#pragma unroll
    for (int it = 0; it < 8; ++it) {
      const int row = it * 8 + (lane >> 3), col = (lane & 7) * 8;
      const float* src = S0 + (size_t)b * 4096 + row * 64 + col;
      const float4 v1 = *(const float4*)src;
      const float4 v2 = *(const float4*)(src + 4);
      f16x8 pk;
      pk[0] = (_Float16)v1.x; pk[1] = (_Float16)v1.y;
      pk[2] = (_Float16)v1.z; pk[3] = (_Float16)v1.w;
      pk[4] = (_Float16)v2.x; pk[5] = (_Float16)v2.y;
      pk[6] = (_Float16)v2.z; pk[7] = (_Float16)v2.w;
      *(f16x8*)&sSW[row][col] = pk;
    }
  }

  // ---------------- phase O ----------------
  stage64(sK, t0o, 0);
  stage64(sQ, t0o, 128);
  stage64(sV, t0o, 64);

#pragma unroll
  for (int ti = 0; ti < 4; ++ti)
#pragma unroll
    for (int tj = 0; tj < 4; ++tj) {
      f32x4 a = dotT(&sK[0][0], 72, ti * 16, &sSW[0][0], 72, tj * 16);
#pragma unroll
      for (int r = 0; r < 4; ++r) {
        const int t = ti * 16 + fg * 4 + r, i = tj * 16 + fr;
        const float vo = (float)sV[t][i];
        sV[t][i] = (_Float16)(vo - powA((float)t) * a[r]);
      }
    }

  f32x4 sq[16];
#pragma unroll
  for (int ti = 0; ti < 4; ++ti)
#pragma unroll
    for (int tj = 0; tj < 4; ++tj) {
      f32x4 a = dotT(&sQ[0][0], 72, ti * 16, &sSW[0][0], 72, tj * 16);
#pragma unroll
      for (int r = 0; r < 4; ++r)
        a[r] *= powA((float)(ti * 16 + fg * 4 + r + 1));
      sq[ti * 4 + tj] = a;
    }

  solve(false);

#pragma unroll
  for (int tb = 0; tb < 4; ++tb)
#pragma unroll
    for (int qb = 0; qb < 4; ++qb) {
      if (qb <= tb) {
        f32x4 h = dotT(&sQ[0][0], 72, tb * 16, &sK[0][0], 72, qb * 16);
#pragma unroll
        for (int r = 0; r < 4; ++r) {
          const int tl = fg * 4 + r;
          const int t = tb * 16 + tl, tau = qb * 16 + fr;
          const float val = (tau <= t) ? h[r] * powA((float)(t - tau)) : 0.f;
          sGt[tl][fr] = (_Float16)val;
        }
#pragma unroll
        for (int ib = 0; ib < 4; ++ib) {
          f16x8 af = *(const f16x8*)&sGt[fr][fg * 8];
          f16x8 bf = *(const f16x8*)&sDT[ib * 16 + fr][qb * 16 + fg * 8];
          sq[tb * 4 + ib] = __builtin_amdgcn_mfma_f32_16x16x32_f16(af, bf, sq[tb * 4 + ib], 0, 0, 0);
        }
      }
    }

#pragma unroll
  for (int ti = 0; ti < 4; ++ti)
#pragma unroll
    for (int tj = 0; tj < 4; ++tj)
#pragma unroll
      for (int r = 0; r < 4; ++r) {
        const int t = ti * 16 + fg * 4 + r, i = tj * 16 + fr;
        const float Sq = sq[ti * 4 + tj][r];
        const float sig = 1.0f / (1.0f + __expf(-Sq));
        out[(size_t)(t0o + t) * 1024 + b * 64 + i] = Sq * Sq * sig;
      }

  if (c == NCHUNK - 1) {
#pragma unroll
    for (int t8 = 0; t8 < 8; ++t8) {
      f16x8 v = *(const f16x8*)&sDT[lane][t8 * 8];
#pragma unroll
      for (int e = 0; e < 8; ++e)
        v[e] = (_Float16)((float)v[e] * powA((float)(63 - (t8 * 8 + e))));
      *(f16x8*)&sDT[lane][t8 * 8] = v;
    }
    transposeK();
#pragma unroll
    for (int ti = 0; ti < 4; ++ti)
#pragma unroll
      for (int tj = 0; tj < 4; ++tj) {
        f32x4 so = dotT(&sDT[0][0], 80, ti * 16, &sQ[0][0], 72, tj * 16);
#pragma unroll
        for (int r = 0; r < 4; ++r) {
          const int i = ti * 16 + fg * 4 + r, j = tj * 16 + fr;
          Sfin[((size_t)b * 64 + i) * 64 + j] = A64F * (float)sSW[i][j] + so[r];
        }
      }
  }
}

extern "C" void kernel_launch(void* const* d_in, const int* in_sizes, int n_in,
                              void* d_out, int out_size, void* d_ws, size_t ws_size,
                              hipStream_t stream)
{
  const float* x  = (const float*)d_in[0];
  const float* S0 = (const float*)d_in[1];
  const float* Wk = (const float*)d_in[2];
  float* out  = (float*)d_out;
  float* Sfin = out + (size_t)T_DIM * B_DIM * N_DIM;

  // ws layout: pf16 (25.17 MB) | w16 (384 KB)
  char* wsb = (char*)d_ws;
  _Float16* pf16 = (_Float16*)(wsb);
  _Float16* w16  = (_Float16*)(wsb + 25165824);

  convert_w<<<(NPROJ * D_DIM) / 256, 256, 0, stream>>>(Wk, w16);
  proj_gemm<<<(T_DIM * B_DIM) / BM, 512, 0, stream>>>(x, w16, pf16);
  prep_kernel<<<(T_DIM * B_DIM) / 4, 256, 0, stream>>>(pf16);
  scan_sw<<<B_DIM * NCHUNK, 64, 0, stream>>>(pf16, S0, out, Sfin);
}